// Round 15
// baseline (379.253 us; speedup 1.0000x reference)
//
#include <hip/hip_runtime.h>

// Transformer_67748814127473 — round 14: R13 + attn_even_k restructured to
// 512 single-slice blocks (8 j-part waves, 8-way combine) for the last layer
// (restores 2 blocks/CU occupancy); pred_k batched 4 rows/block.
// B=8, T=1024, N=2048, E=256, L=4.

#define BB 8
#define TT 1024
#define NN 2048
#define EE 256
#define LL 4
#define YST 258

typedef __attribute__((ext_vector_type(8))) short short8;
typedef __attribute__((ext_vector_type(4))) float f32x4;

__device__ inline ushort f2b(float f) {
    union { float f; unsigned u; } x; x.f = f;
    unsigned u = x.u;
    return (ushort)((u + 0x7fffu + ((u >> 16) & 1u)) >> 16);
}
__device__ inline unsigned cvtpk(float lo, float hi) {
    unsigned r;
    asm volatile("v_cvt_pk_bf16_f32 %0, %1, %2" : "=v"(r) : "v"(lo), "v"(hi));
    return r;
}
// fragment-linear pack for K=256 operands: tile16(row) x kchunk32 -> [lane][8]
__device__ inline size_t pk256(int row, int k) {
    return ((size_t)((row >> 4) * 8 + (k >> 5))) * 512
         + (size_t)((((k >> 3) & 3) * 16 + (row & 15)) * 8 + (k & 7));
}
// V pack: (batch, token n, embed e) -> B-frag linear
__device__ inline size_t vpk_idx(int bb, int nn, int e) {
    return ((size_t)(bb*64 + (nn >> 5)) * 16 + (e >> 4)) * 512
         + (size_t)((((nn >> 3) & 3) * 16 + (e & 15)) * 8 + (nn & 7));
}

// ---------------- weight prep: transpose + cast + frag-pack ----------------
__global__ __launch_bounds__(256) void wprep_k(
    const float* __restrict__ Wq, const float* __restrict__ Wk,
    const float* __restrict__ Wv, const float* __restrict__ W1,
    const float* __restrict__ W2,
    ushort* __restrict__ WQKt, ushort* __restrict__ WVt,
    ushort* __restrict__ W1t, ushort* __restrict__ W2t)
{
    int id = blockIdx.x;          // 320 = 20 matrices x 16 tiles
    int m = id >> 4, t = id & 15;
    int l = m / 5, which = m % 5;
    const float* src; ushort* dst;
    size_t o = (size_t)l * 65536;
    switch (which) {
        case 0: src = Wq + o; dst = WQKt + (size_t)l*131072;          break;
        case 1: src = Wk + o; dst = WQKt + (size_t)l*131072 + 65536;  break;
        case 2: src = Wv + o; dst = WVt + o; break;
        case 3: src = W1 + o; dst = W1t + o; break;
        default: src = W2 + o; dst = W2t + o; break;
    }
    int tk = (t >> 2) * 64;   // k block
    int tn = (t & 3) * 64;    // n block (output col)
    __shared__ ushort T[64][68];
    int tid = threadIdx.x;
    int r = tid >> 4, c4 = (tid & 15) * 4;
    #pragma unroll
    for (int it = 0; it < 4; ++it) {
        int k = r + it*16;
        float4 v = *(const float4*)&src[(size_t)(tk + k)*256 + tn + c4];
        T[k][c4+0] = f2b(v.x); T[k][c4+1] = f2b(v.y);
        T[k][c4+2] = f2b(v.z); T[k][c4+3] = f2b(v.w);
    }
    __syncthreads();
    #pragma unroll
    for (int it = 0; it < 4; ++it) {
        int n = tn + r + it*16;
        int k0 = tk + c4;
        ushort4 ov;
        ov.x = T[c4+0][n-tn]; ov.y = T[c4+1][n-tn];
        ov.z = T[c4+2][n-tn]; ov.w = T[c4+3][n-tn];
        *(ushort4*)&dst[pk256(n, k0)] = ov;
    }
}

// ---------------- per-batch even-row base vector ----------------
__global__ __launch_bounds__(256) void base_even_k(
    const float* __restrict__ aset, const float* __restrict__ We,
    const float* __restrict__ be, float* __restrict__ BE)
{
    int b = blockIdx.x; int e = threadIdx.x;
    __shared__ float as[640];
    for (int i = e; i < 640; i += 256) as[i] = aset[b*640 + i];
    __syncthreads();
    float s = We[651*EE + e] + be[e];
    for (int f = 0; f < 640; ++f) s = fmaf(as[f], We[f*EE + e], s);
    BE[b*EE + e] = s;
}

// ---------------- embedding (8 rows per block), fp32 + packed bf16 ----------
__global__ __launch_bounds__(256) void embed_k(
    const float* __restrict__ BE, const float* __restrict__ ca,
    const float* __restrict__ cr, const float* __restrict__ We,
    const float* __restrict__ be, const float* __restrict__ wpe,
    float* __restrict__ H, ushort* __restrict__ Hbf)
{
    int e = threadIdx.x;
    #pragma unroll
    for (int k = 0; k < 8; ++k) {
        int rb = blockIdx.x * 8 + k;
        int b = rb >> 11, n = rb & (NN-1);
        float h;
        if ((n & 1) == 0) {
            h = BE[b*EE + e];
        } else {
            int t = n >> 1;
            h = We[651*EE + e] + be[e];
            const float* cap = ca + (size_t)(b*TT + t)*10;
            #pragma unroll
            for (int i = 0; i < 10; ++i) h = fmaf(cap[i], We[(640+i)*EE + e], h);
            h = fmaf(cr[b*TT + t], We[650*EE + e], h);
        }
        h = fmaf((float)(n + 1), We[652*EE + e], h);
        h += wpe[(size_t)n*EE + e];
        H[(size_t)rb*EE + e] = h;
        Hbf[pk256(rb, e)] = f2b(h);
    }
}

// ---------------- merged QKV GEMM (packed in, packed out) -------------------
__global__ __launch_bounds__(256, 2) void qkv_k(
    const ushort* __restrict__ A, const ushort* __restrict__ WQK,
    const ushort* __restrict__ WV,
    ushort* __restrict__ Qo, ushort* __restrict__ Ko, ushort* __restrict__ Vo)
{
    int tid = threadIdx.x;
    int w = tid >> 6, l = tid & 63;
    int lr = l & 15, lg = l >> 4;
    int wr = w >> 1, wc = w & 1;
    int rt0 = blockIdx.x * 8 + wr*4;
    int ct0 = blockIdx.y * 8 + wc*4;
    const ushort* Ap = A + (size_t)rt0*4096 + l*8;
    const ushort* Bp = (blockIdx.y < 4 ? WQK + (size_t)ct0*4096
                                       : WV + (size_t)(ct0-32)*4096) + l*8;
    f32x4 acc[4][4];
    #pragma unroll
    for (int i = 0; i < 4; ++i)
        #pragma unroll
        for (int j = 0; j < 4; ++j) acc[i][j] = (f32x4){0.f,0.f,0.f,0.f};
    #pragma unroll
    for (int kc = 0; kc < 8; ++kc) {
        short8 af[4], bf[4];
        #pragma unroll
        for (int rg = 0; rg < 4; ++rg) af[rg] = *(const short8*)(Ap + (size_t)rg*4096 + kc*512);
        #pragma unroll
        for (int cg = 0; cg < 4; ++cg) bf[cg] = *(const short8*)(Bp + (size_t)cg*4096 + kc*512);
        #pragma unroll
        for (int rg = 0; rg < 4; ++rg)
            #pragma unroll
            for (int cg = 0; cg < 4; ++cg)
                acc[rg][cg] = __builtin_amdgcn_mfma_f32_16x16x32_bf16(af[rg], bf[cg], acc[rg][cg], 0,0,0);
    }
    #pragma unroll
    for (int rg = 0; rg < 4; ++rg)
        #pragma unroll
        for (int cg = 0; cg < 4; ++cg)
            #pragma unroll
            for (int r = 0; r < 4; ++r) {
                int row = rt0*16 + rg*16 + lg*4 + r;
                int col = ct0*16 + cg*16 + lr;
                ushort xv = f2b(acc[rg][cg][r]);
                if (col < 256)      Qo[pk256(row, col)] = xv;
                else if (col < 512) Ko[pk256(row, col - 256)] = xv;
                else {
                    int e = col - 512, bb = row >> 11, nn = row & (NN-1);
                    Vo[vpk_idx(bb, nn, e)] = xv;
                }
            }
}

// ---------------- full layer tail (all rows): R12/R13 structure -------------
__global__ __launch_bounds__(512, 2) void attn_k(
    const ushort* Qp, const ushort* __restrict__ Kp,
    const ushort* __restrict__ Vp, const float* H,
    const float* __restrict__ g, const float* __restrict__ bt,
    const ushort* __restrict__ W1t, const float* __restrict__ b1p,
    const ushort* __restrict__ W2t, const float* __restrict__ b2p,
    const float* __restrict__ g2, const float* __restrict__ bt2,
    float* Hout, ushort* __restrict__ Hpk)
{
    int blk = blockIdx.x;            // pk*8 + b
    int pk = blk >> 3, b = blk & 7;
    int tid = threadIdx.x;
    int w = tid >> 6, l = tid & 63;
    int lr = l & 15, lg = l >> 4;
    int sel  = (w & 1) ^ ((w >> 2) & 1);
    int part = w >> 1;
    int s  = sel ? (127 - pk) : pk;
    int i0 = s * 16;
    int NT = (s >> 1) + 1;
    int j0 = (part * NT) >> 2;
    int j1 = ((part + 1) * NT) >> 2;

    __shared__ float comb[2][5440];
    __shared__ ushort ylds[2][4096];
    __shared__ float red2[2][16][4][2];

    const ushort* Kbase = Kp + (size_t)(b*128) * 4096 + l*8;
    const ushort* Vbase = Vp + (size_t)(b*64) * 16 * 512 + l*8;

    short8 qb[8];
    {
        const ushort* Qt = Qp + ((size_t)(b*128 + s)) * 4096 + l*8;
        #pragma unroll
        for (int kc = 0; kc < 8; ++kc) qb[kc] = *(const short8*)(Qt + kc*512);
    }

    f32x4 oacc[16];
    #pragma unroll
    for (int et = 0; et < 16; ++et) oacc[et] = (f32x4){0.f,0.f,0.f,0.f};

    int ig = i0 + lr;
    for (int jt = j0; jt < j1; ++jt) {
        const ushort* Kt = Kbase + (size_t)(jt*2) * 4096;
        short8 ka0[8], ka1[8];
        #pragma unroll
        for (int kc = 0; kc < 8; ++kc) {
            ka0[kc] = *(const short8*)(Kt + kc*512);
            ka1[kc] = *(const short8*)(Kt + 4096 + kc*512);
        }
        const ushort* Vt = Vbase + (size_t)(jt*16) * 512;
        short8 vf[16];
        #pragma unroll
        for (int et = 0; et < 16; ++et)
            vf[et] = *(const short8*)(Vt + et*512);
        f32x4 c0a = {0.f,0.f,0.f,0.f}, c0b = {0.f,0.f,0.f,0.f};
        f32x4 c1a = {0.f,0.f,0.f,0.f}, c1b = {0.f,0.f,0.f,0.f};
        #pragma unroll
        for (int kc = 0; kc < 8; kc += 2) {
            c0a = __builtin_amdgcn_mfma_f32_16x16x32_bf16(ka0[kc],   qb[kc],   c0a, 0,0,0);
            c0b = __builtin_amdgcn_mfma_f32_16x16x32_bf16(ka0[kc+1], qb[kc+1], c0b, 0,0,0);
            c1a = __builtin_amdgcn_mfma_f32_16x16x32_bf16(ka1[kc],   qb[kc],   c1a, 0,0,0);
            c1b = __builtin_amdgcn_mfma_f32_16x16x32_bf16(ka1[kc+1], qb[kc+1], c1b, 0,0,0);
        }
        f32x4 c0 = c0a + c0b, c1 = c1a + c1b;
        #pragma unroll
        for (int r = 0; r < 4; ++r) {
            int jg = jt*32 + lg*4 + r;
            c0[r] = (jg <= ig) ? fmaxf(c0[r], 0.f) : 0.f;
            c1[r] = (jg + 16 <= ig) ? fmaxf(c1[r], 0.f) : 0.f;
        }
        unsigned u0 = cvtpk(c0[0], c0[1]), u1 = cvtpk(c0[2], c0[3]);
        unsigned u2 = cvtpk(c1[0], c1[1]), u3 = cvtpk(c1[2], c1[3]);
        int srcA = 32*(lg & 1) + lr;
        int srcB = srcA + 16;
        unsigned a0A = __shfl((int)u0, srcA), a1A = __shfl((int)u1, srcA);
        unsigned a0B = __shfl((int)u0, srcB), a1B = __shfl((int)u1, srcB);
        unsigned b0A = __shfl((int)u2, srcA), b1A = __shfl((int)u3, srcA);
        unsigned b0B = __shfl((int)u2, srcB), b1B = __shfl((int)u3, srcB);
        bool lo = (lg < 2);
        union { unsigned u[4]; short8 v; } sv;
        sv.u[0] = lo ? a0A : b0A;
        sv.u[1] = lo ? a1A : b1A;
        sv.u[2] = lo ? a0B : b0B;
        sv.u[3] = lo ? a1B : b1B;
        short8 sa = sv.v;
        __builtin_amdgcn_s_setprio(1);
        #pragma unroll
        for (int et = 0; et < 16; ++et)
            oacc[et] = __builtin_amdgcn_mfma_f32_16x16x32_bf16(sa, vf[et], oacc[et], 0,0,0);
        __builtin_amdgcn_s_setprio(0);
    }

    float* cb = &comb[sel][0];
    #pragma unroll
    for (int rnd = 1; rnd <= 3; ++rnd) {
        if (part == rnd) {
            #pragma unroll
            for (int et = 0; et < 16; ++et)
                #pragma unroll
                for (int r = 0; r < 4; ++r) {
                    int idx = et*340 + l*5 + r;
                    float v = oacc[et][r];
                    if (rnd == 1) cb[idx] = v; else cb[idx] += v;
                }
        }
        __syncthreads();
    }
    if (part == 0) {
        float sm[4] = {0.f,0.f,0.f,0.f}, sq[4] = {0.f,0.f,0.f,0.f};
        #pragma unroll
        for (int et = 0; et < 16; ++et)
            #pragma unroll
            for (int r = 0; r < 4; ++r) {
                int irow = i0 + lg*4 + r;
                size_t base = ((size_t)(b*NN + irow))*EE + et*16 + lr;
                float x = H[base] + (oacc[et][r] + cb[et*340 + l*5 + r])
                                    * (1.0f / (float)(irow + 1));
                oacc[et][r] = x;
                sm[r] += x; sq[r] += x*x;
            }
        #pragma unroll
        for (int off = 1; off < 16; off <<= 1)
            #pragma unroll
            for (int r = 0; r < 4; ++r) {
                sm[r] += __shfl_xor(sm[r], off);
                sq[r] += __shfl_xor(sq[r], off);
            }
        float mean[4], inv[4];
        #pragma unroll
        for (int r = 0; r < 4; ++r) {
            mean[r] = sm[r] * (1.0f/256.0f);
            float var = sq[r] * (1.0f/256.0f) - mean[r]*mean[r];
            inv[r] = 1.0f / sqrtf(var + 1e-5f);
        }
        ushort* yl = &ylds[sel][0];
        #pragma unroll
        for (int et = 0; et < 16; ++et) {
            int col = et*16 + lr;
            float gv = g[col], bv = bt[col];
            #pragma unroll
            for (int r = 0; r < 4; ++r) {
                int row16 = lg*4 + r;
                float y = (oacc[et][r] - mean[r]) * inv[r] * gv + bv;
                cb[row16*YST + col] = y;
                int idx = (col >> 5)*512 + ((((col >> 3) & 3) << 4) + row16)*8
                        + (col & 7);
                yl[idx] = f2b(y);
            }
        }
    }
    __syncthreads();
    f32x4 macc[4];
    {
        const ushort* Ay = &ylds[sel][0] + l*8;
        const ushort* Bp = W1t + (size_t)(part*4)*4096 + l*8;
        #pragma unroll
        for (int cg = 0; cg < 4; ++cg) macc[cg] = (f32x4){0.f,0.f,0.f,0.f};
        #pragma unroll
        for (int kc = 0; kc < 8; ++kc) {
            short8 af = *(const short8*)(Ay + kc*512);
            #pragma unroll
            for (int cg = 0; cg < 4; ++cg) {
                short8 bf = *(const short8*)(Bp + (size_t)cg*4096 + kc*512);
                macc[cg] = __builtin_amdgcn_mfma_f32_16x16x32_bf16(af, bf, macc[cg], 0,0,0);
            }
        }
    }
    __syncthreads();
    {
        ushort* yl = &ylds[sel][0];
        #pragma unroll
        for (int cg = 0; cg < 4; ++cg)
            #pragma unroll
            for (int r = 0; r < 4; ++r) {
                int col = part*64 + cg*16 + lr;
                int row16 = lg*4 + r;
                float x = fmaxf(macc[cg][r] + b1p[col], 0.f);
                int idx = (col >> 5)*512 + ((((col >> 3) & 3) << 4) + row16)*8
                        + (col & 7);
                yl[idx] = f2b(x);
            }
    }
    __syncthreads();
    float x2[4][4];
    {
        const ushort* Am = &ylds[sel][0] + l*8;
        const ushort* Bp = W2t + (size_t)(part*4)*4096 + l*8;
        f32x4 m2[4];
        #pragma unroll
        for (int cg = 0; cg < 4; ++cg) m2[cg] = (f32x4){0.f,0.f,0.f,0.f};
        #pragma unroll
        for (int kc = 0; kc < 8; ++kc) {
            short8 af = *(const short8*)(Am + kc*512);
            #pragma unroll
            for (int cg = 0; cg < 4; ++cg) {
                short8 bf = *(const short8*)(Bp + (size_t)cg*4096 + kc*512);
                m2[cg] = __builtin_amdgcn_mfma_f32_16x16x32_bf16(af, bf, m2[cg], 0,0,0);
            }
        }
        float sm2[4] = {0.f,0.f,0.f,0.f}, sq2[4] = {0.f,0.f,0.f,0.f};
        #pragma unroll
        for (int cg = 0; cg < 4; ++cg)
            #pragma unroll
            for (int r = 0; r < 4; ++r) {
                int col = part*64 + cg*16 + lr;
                int row16 = lg*4 + r;
                float v = m2[cg][r] + b2p[col] + cb[row16*YST + col];
                x2[cg][r] = v;
                sm2[r] += v; sq2[r] += v*v;
            }
        #pragma unroll
        for (int off = 1; off < 16; off <<= 1)
            #pragma unroll
            for (int r = 0; r < 4; ++r) {
                sm2[r] += __shfl_xor(sm2[r], off);
                sq2[r] += __shfl_xor(sq2[r], off);
            }
        if (lr == 0) {
            #pragma unroll
            for (int r = 0; r < 4; ++r) {
                red2[sel][lg*4 + r][part][0] = sm2[r];
                red2[sel][lg*4 + r][part][1] = sq2[r];
            }
        }
    }
    __syncthreads();
    {
        float mean[4], inv[4];
        #pragma unroll
        for (int r = 0; r < 4; ++r) {
            int row16 = lg*4 + r;
            float S  = red2[sel][row16][0][0] + red2[sel][row16][1][0]
                     + red2[sel][row16][2][0] + red2[sel][row16][3][0];
            float S2 = red2[sel][row16][0][1] + red2[sel][row16][1][1]
                     + red2[sel][row16][2][1] + red2[sel][row16][3][1];
            mean[r] = S * (1.0f/256.0f);
            float var = S2 * (1.0f/256.0f) - mean[r]*mean[r];
            inv[r] = 1.0f / sqrtf(var + 1e-5f);
        }
        #pragma unroll
        for (int cg = 0; cg < 4; ++cg) {
            int col = part*64 + cg*16 + lr;
            float gv = g2[col], bv = bt2[col];
            #pragma unroll
            for (int r = 0; r < 4; ++r) {
                int irow = i0 + lg*4 + r;
                size_t base = ((size_t)(b*NN + irow))*EE + col;
                float y2 = (x2[cg][r] - mean[r]) * inv[r] * gv + bv;
                Hout[base] = y2;
                Hpk[pk256(b*NN + irow, col)] = f2b(y2);
            }
        }
    }
}

// ---------------- last layer: even rows only, single slice, 8 j-parts -------
// 512 blocks: bk<256 -> sv=pk, bk>=256 -> sv=63-pk (complementary pairs land
// on the same CU under round-robin). Wave covers 16 EVEN rows of the 32-row
// window sv; 8 waves = 8 j-parts; 8-way combine; tail 8 x 32-col split.
__global__ __launch_bounds__(512, 2) void attn_even_k(
    const ushort* Qp, const ushort* __restrict__ Kp,
    const ushort* __restrict__ Vp, const float* H,
    const float* __restrict__ g, const float* __restrict__ bt,
    const ushort* __restrict__ W1t, const float* __restrict__ b1p,
    const ushort* __restrict__ W2t, const float* __restrict__ b2p,
    const float* __restrict__ g2, const float* __restrict__ bt2,
    float* Hout, ushort* __restrict__ Hpk)
{
    int bk = blockIdx.x;
    int half = bk >> 8;
    int idx8 = bk & 255;
    int pk = idx8 >> 3, b = idx8 & 7;
    int sv = half ? (63 - pk) : pk;      // 32-row window index
    int tid = threadIdx.x;
    int part = tid >> 6, l = tid & 63;   // 8 j-parts
    int lr = l & 15, lg = l >> 4;
    int i0 = sv * 32;
    int NT = sv + 1;                     // causal j-tiles of 32
    int j0 = (part * NT) >> 3;
    int j1 = ((part + 1) * NT) >> 3;

    __shared__ float comb[5440];         // 21.8 KB: combine, then y fp32
    __shared__ ushort ylds[4096];        // 8 KB: y frags, then mid frags
    __shared__ float red2[16][8][2];     // 1 KB

    const ushort* Kbase = Kp + (size_t)(b*128) * 4096 + l*8;
    const ushort* Vbase = Vp + (size_t)(b*64) * 16 * 512 + l*8;

    short8 qb[8];
    {
        const ushort* Qb0 = Qp + (size_t)(b*128) * 4096;
        int qrow = i0 + 2*lr;
        #pragma unroll
        for (int kc = 0; kc < 8; ++kc)
            qb[kc] = *(const short8*)&Qb0[pk256(qrow, kc*32 + lg*8)];
    }

    f32x4 oacc[16];
    #pragma unroll
    for (int et = 0; et < 16; ++et) oacc[et] = (f32x4){0.f,0.f,0.f,0.f};

    int ig = i0 + 2*lr;
    for (int jt = j0; jt < j1; ++jt) {
        const ushort* Kt = Kbase + (size_t)(jt*2) * 4096;
        short8 ka0[8], ka1[8];
        #pragma unroll
        for (int kc = 0; kc < 8; ++kc) {
            ka0[kc] = *(const short8*)(Kt + kc*512);
            ka1[kc] = *(const short8*)(Kt + 4096 + kc*512);
        }
        const ushort* Vt = Vbase + (size_t)(jt*16) * 512;
        short8 vf[16];
        #pragma unroll
        for (int et = 0; et < 16; ++et)
            vf[et] = *(const short8*)(Vt + et*512);
        f32x4 c0a = {0.f,0.f,0.f,0.f}, c0b = {0.f,0.f,0.f,0.f};
        f32x4 c1a = {0.f,0.f,0.f,0.f}, c1b = {0.f,0.f,0.f,0.f};
        #pragma unroll
        for (int kc = 0; kc < 8; kc += 2) {
            c0a = __builtin_amdgcn_mfma_f32_16x16x32_bf16(ka0[kc],   qb[kc],   c0a, 0,0,0);
            c0b = __builtin_amdgcn_mfma_f32_16x16x32_bf16(ka0[kc+1], qb[kc+1], c0b, 0,0,0);
            c1a = __builtin_amdgcn_mfma_f32_16x16x32_bf16(ka1[kc],   qb[kc],   c1a, 0,0,0);
            c1b = __builtin_amdgcn_mfma_f32_16x16x32_bf16(ka1[kc+1], qb[kc+1], c1b, 0,0,0);
        }
        f32x4 c0 = c0a + c0b, c1 = c1a + c1b;
        #pragma unroll
        for (int r = 0; r < 4; ++r) {
            int jg = jt*32 + lg*4 + r;
            c0[r] = (jg <= ig) ? fmaxf(c0[r], 0.f) : 0.f;
            c1[r] = (jg + 16 <= ig) ? fmaxf(c1[r], 0.f) : 0.f;
        }
        unsigned u0 = cvtpk(c0[0], c0[1]), u1 = cvtpk(c0[2], c0[3]);
        unsigned u2 = cvtpk(c1[0], c1[1]), u3 = cvtpk(c1[2], c1[3]);
        int srcA = 32*(lg & 1) + lr;
        int srcB = srcA + 16;
        unsigned a0A = __shfl((int)u0, srcA), a1A = __shfl((int)u1, srcA);
        unsigned a0B = __shfl((int)u0, srcB), a1B = __shfl((int)u1, srcB);
        unsigned b0A = __shfl((int)u2, srcA), b1A = __shfl((int)u3, srcA);
        unsigned b0B = __shfl((int)u2, srcB), b1B = __shfl((int)u3, srcB);
        bool lo = (lg < 2);
        union { unsigned u[4]; short8 v; } sv2;
        sv2.u[0] = lo ? a0A : b0A;
        sv2.u[1] = lo ? a1A : b1A;
        sv2.u[2] = lo ? a0B : b0B;
        sv2.u[3] = lo ? a1B : b1B;
        short8 sa = sv2.v;
        __builtin_amdgcn_s_setprio(1);
        #pragma unroll
        for (int et = 0; et < 16; ++et)
            oacc[et] = __builtin_amdgcn_mfma_f32_16x16x32_bf16(sa, vf[et], oacc[et], 0,0,0);
        __builtin_amdgcn_s_setprio(0);
    }

    // ---- 8-way combine (parts 1..7 -> LDS) ----
    #pragma unroll
    for (int rnd = 1; rnd <= 7; ++rnd) {
        if (part == rnd) {
            #pragma unroll
            for (int et = 0; et < 16; ++et)
                #pragma unroll
                for (int r = 0; r < 4; ++r) {
                    int idx = et*340 + l*5 + r;
                    float v = oacc[et][r];
                    if (rnd == 1) comb[idx] = v; else comb[idx] += v;
                }
        }
        __syncthreads();
    }
    // ---- epilogue by part 0: residual + scale + LN1 -> comb(y) + ylds ----
    if (part == 0) {
        float sm[4] = {0.f,0.f,0.f,0.f}, sq[4] = {0.f,0.f,0.f,0.f};
        #pragma unroll
        for (int et = 0; et < 16; ++et)
            #pragma unroll
            for (int r = 0; r < 4; ++r) {
                int irow = i0 + 2*(lg*4 + r);
                size_t base = ((size_t)(b*NN + irow))*EE + et*16 + lr;
                float x = H[base] + (oacc[et][r] + comb[et*340 + l*5 + r])
                                    * (1.0f / (float)(irow + 1));
                oacc[et][r] = x;
                sm[r] += x; sq[r] += x*x;
            }
        #pragma unroll
        for (int off = 1; off < 16; off <<= 1)
            #pragma unroll
            for (int r = 0; r < 4; ++r) {
                sm[r] += __shfl_xor(sm[r], off);
                sq[r] += __shfl_xor(sq[r], off);
            }
        float mean[4], inv[4];
        #pragma unroll
        for (int r = 0; r < 4; ++r) {
            mean[r] = sm[r] * (1.0f/256.0f);
            float var = sq[r] * (1.0f/256.0f) - mean[r]*mean[r];
            inv[r] = 1.0f / sqrtf(var + 1e-5f);
        }
        #pragma unroll
        for (int et = 0; et < 16; ++et) {
            int col = et*16 + lr;
            float gv = g[col], bv = bt[col];
            #pragma unroll
            for (int r = 0; r < 4; ++r) {
                int row16 = lg*4 + r;
                float y = (oacc[et][r] - mean[r]) * inv[r] * gv + bv;
                comb[row16*YST + col] = y;
                int idx = (col >> 5)*512 + ((((col >> 3) & 3) << 4) + row16)*8
                        + (col & 7);
                ylds[idx] = f2b(y);
            }
        }
    }
    __syncthreads();
    // ---- mlp1: 8 waves x 32 cols ----
    f32x4 macc[2];
    {
        const ushort* Ay = &ylds[0] + l*8;
        const ushort* Bp = W1t + (size_t)(part*2)*4096 + l*8;
        #pragma unroll
        for (int cg = 0; cg < 2; ++cg) macc[cg] = (f32x4){0.f,0.f,0.f,0.f};
        #pragma unroll
        for (int kc = 0; kc < 8; ++kc) {
            short8 af = *(const short8*)(Ay + kc*512);
            #pragma unroll
            for (int cg = 0; cg < 2; ++cg) {
                short8 bf = *(const short8*)(Bp + (size_t)cg*4096 + kc*512);
                macc[cg] = __builtin_amdgcn_mfma_f32_16x16x32_bf16(af, bf, macc[cg], 0,0,0);
            }
        }
    }
    __syncthreads();
    {
        #pragma unroll
        for (int cg = 0; cg < 2; ++cg)
            #pragma unroll
            for (int r = 0; r < 4; ++r) {
                int col = part*32 + cg*16 + lr;
                int row16 = lg*4 + r;
                float x = fmaxf(macc[cg][r] + b1p[col], 0.f);
                int idx = (col >> 5)*512 + ((((col >> 3) & 3) << 4) + row16)*8
                        + (col & 7);
                ylds[idx] = f2b(x);
            }
    }
    __syncthreads();
    // ---- mlp2 + b2 + y-residual, then ln2 ----
    float x2[2][4];
    {
        const ushort* Am = &ylds[0] + l*8;
        const ushort* Bp = W2t + (size_t)(part*2)*4096 + l*8;
        f32x4 m2[2];
        #pragma unroll
        for (int cg = 0; cg < 2; ++cg) m2[cg] = (f32x4){0.f,0.f,0.f,0.f};
        #pragma unroll
        for (int kc = 0; kc < 8; ++kc) {
            short8 af = *(const short8*)(Am + kc*512);
            #pragma unroll
            for (int cg = 0; cg < 2; ++cg) {
                short8 bf = *(const short8*)(Bp + (size_t)cg*4096 + kc*512);
                m2[cg] = __builtin_amdgcn_mfma_f32_16x16x32_bf16(af, bf, m2[cg], 0,0,0);
            }
        }
        float sm2[4] = {0.f,0.f,0.f,0.f}, sq2[4] = {0.f,0.f,0.f,0.f};
        #pragma unroll
        for (int cg = 0; cg < 2; ++cg)
            #pragma unroll
            for (int r = 0; r < 4; ++r) {
                int col = part*32 + cg*16 + lr;
                int row16 = lg*4 + r;
                float v = m2[cg][r] + b2p[col] + comb[row16*YST + col];
                x2[cg][r] = v;
                sm2[r] += v; sq2[r] += v*v;
            }
        #pragma unroll
        for (int off = 1; off < 16; off <<= 1)
            #pragma unroll
            for (int r = 0; r < 4; ++r) {
                sm2[r] += __shfl_xor(sm2[r], off);
                sq2[r] += __shfl_xor(sq2[r], off);
            }
        if (lr == 0) {
            #pragma unroll
            for (int r = 0; r < 4; ++r) {
                red2[lg*4 + r][part][0] = sm2[r];
                red2[lg*4 + r][part][1] = sq2[r];
            }
        }
    }
    __syncthreads();
    {
        float mean[4], inv[4];
        #pragma unroll
        for (int r = 0; r < 4; ++r) {
            int row16 = lg*4 + r;
            float S = 0.f, S2 = 0.f;
            #pragma unroll
            for (int p2 = 0; p2 < 8; ++p2) {
                S  += red2[row16][p2][0];
                S2 += red2[row16][p2][1];
            }
            mean[r] = S * (1.0f/256.0f);
            float var = S2 * (1.0f/256.0f) - mean[r]*mean[r];
            inv[r] = 1.0f / sqrtf(var + 1e-5f);
        }
        #pragma unroll
        for (int cg = 0; cg < 2; ++cg) {
            int col = part*32 + cg*16 + lr;
            float gv = g2[col], bv = bt2[col];
            #pragma unroll
            for (int r = 0; r < 4; ++r) {
                int irow = i0 + 2*(lg*4 + r);
                size_t base = ((size_t)(b*NN + irow))*EE + col;
                float y2 = (x2[cg][r] - mean[r]) * inv[r] * gv + bv;
                Hout[base] = y2;
                Hpk[pk256(b*NN + irow, col)] = f2b(y2);
            }
        }
    }
}

// ---------------- prediction head (even rows only), 4 rows per block --------
__global__ __launch_bounds__(256) void pred_k(
    const float* __restrict__ H, const float* __restrict__ Wp,
    const float* __restrict__ bp, float* __restrict__ out)
{
    __shared__ float hs[256];
    __shared__ float pr[16][16];
    int tid = threadIdx.x;
    int c = tid & 15, seg = tid >> 4;
    #pragma unroll
    for (int ii = 0; ii < 4; ++ii) {
        int bt = blockIdx.x * 4 + ii;
        int b = bt >> 10, t = bt & 1023;
        size_t row = (size_t)b*NN + 2*t;
        hs[tid] = H[row*EE + tid];
        __syncthreads();
        float p = 0.f;
        if (c < 10) {
            #pragma unroll
            for (int e2 = 0; e2 < 16; ++e2)
                p = fmaf(hs[seg*16 + e2], Wp[(seg*16 + e2)*10 + c], p);
        }
        pr[seg][c] = p;
        __syncthreads();
        if (tid < 10) {
            float sacc = bp[tid];
            #pragma unroll
            for (int k2 = 0; k2 < 16; ++k2) sacc += pr[k2][tid];
            out[(size_t)bt*10 + tid] = sacc;
        }
        __syncthreads();
    }
}

extern "C" void kernel_launch(void* const* d_in, const int* in_sizes, int n_in,
                              void* d_out, int out_size, void* d_ws, size_t ws_size,
                              hipStream_t stream)
{
    const float* action_set = (const float*)d_in[1];
    const float* ctx_act    = (const float*)d_in[2];
    const float* ctx_rew    = (const float*)d_in[3];
    const float* W_embed    = (const float*)d_in[4];
    const float* b_embed    = (const float*)d_in[5];
    const float* wpe        = (const float*)d_in[6];
    const float* Wq         = (const float*)d_in[7];
    const float* Wk         = (const float*)d_in[8];
    const float* Wv         = (const float*)d_in[9];
    const float* ln1g       = (const float*)d_in[10];
    const float* ln1b       = (const float*)d_in[11];
    const float* W1         = (const float*)d_in[12];
    const float* b1         = (const float*)d_in[13];
    const float* W2         = (const float*)d_in[14];
    const float* b2         = (const float*)d_in[15];
    const float* ln2g       = (const float*)d_in[16];
    const float* ln2b       = (const float*)d_in[17];
    const float* Wp         = (const float*)d_in[18];
    const float* bp         = (const float*)d_in[19];
    float* out = (float*)d_out;

    float* ws = (float*)d_ws;
    const size_t SZ = (size_t)BB*NN*EE;   // 4,194,304
    size_t o = 0;
    float*  Hb   = ws;               o += SZ;
    ushort* Hbf  = (ushort*)(ws+o);  o += SZ/2;
    ushort* Qp   = (ushort*)(ws+o);  o += SZ/2;
    ushort* Kpk  = (ushort*)(ws+o);  o += SZ/2;
    ushort* Vpk  = (ushort*)(ws+o);  o += SZ/2;
    ushort* WQKt = (ushort*)(ws+o);  o += 262144;
    ushort* WVt  = (ushort*)(ws+o);  o += 131072;
    ushort* W1t  = (ushort*)(ws+o);  o += 131072;
    ushort* W2t  = (ushort*)(ws+o);  o += 131072;
    float*  BE   = ws + o;

    wprep_k<<<320, 256, 0, stream>>>(Wq, Wk, Wv, W1, W2, WQKt, WVt, W1t, W2t);
    base_even_k<<<BB, 256, 0, stream>>>(action_set, W_embed, b_embed, BE);
    embed_k<<<BB*NN/8, 256, 0, stream>>>(BE, ctx_act, ctx_rew, W_embed, b_embed, wpe, Hb, Hbf);

    for (int l = 0; l < LL; ++l) {
        qkv_k<<<dim3(128, 6), 256, 0, stream>>>(
            Hbf, WQKt + (size_t)l*131072, WVt + (size_t)l*65536, Qp, Kpk, Vpk);
        if (l < LL-1) {
            attn_k<<<512, 512, 0, stream>>>(
                Qp, Kpk, Vpk, Hb, ln1g + l*EE, ln1b + l*EE,
                W1t + (size_t)l*65536, b1 + l*EE,
                W2t + (size_t)l*65536, b2 + l*EE,
                ln2g + l*EE, ln2b + l*EE, Hb, Hbf);
        } else {
            attn_even_k<<<512, 512, 0, stream>>>(
                Qp, Kpk, Vpk, Hb, ln1g + l*EE, ln1b + l*EE,
                W1t + (size_t)l*65536, b1 + l*EE,
                W2t + (size_t)l*65536, b2 + l*EE,
                ln2g + l*EE, ln2b + l*EE, Hb, Hbf);
        }
    }
    pred_k<<<BB*TT/4, 256, 0, stream>>>(Hb, Wp, bp, out);
}

// Round 16
// 369.075 us; speedup vs baseline: 1.0276x; 1.0276x over previous
//
#include <hip/hip_runtime.h>

// Transformer_67748814127473 — round 15: revert to R13 (best measured 368.7us).
// Full layer-tail fusion (attn + ln1 + mlp1 + mlp2 + ln2 in one kernel),
// y-region LDS stride 258, last layer computes even rows only.
// B=8, T=1024, N=2048, E=256, L=4.

#define BB 8
#define TT 1024
#define NN 2048
#define EE 256
#define LL 4
#define YST 258   // y fp32 LDS stride

typedef __attribute__((ext_vector_type(8))) short short8;
typedef __attribute__((ext_vector_type(4))) float f32x4;

__device__ inline ushort f2b(float f) {
    union { float f; unsigned u; } x; x.f = f;
    unsigned u = x.u;
    return (ushort)((u + 0x7fffu + ((u >> 16) & 1u)) >> 16);
}
__device__ inline unsigned cvtpk(float lo, float hi) {
    unsigned r;
    asm volatile("v_cvt_pk_bf16_f32 %0, %1, %2" : "=v"(r) : "v"(lo), "v"(hi));
    return r;
}
// fragment-linear pack for K=256 operands: tile16(row) x kchunk32 -> [lane][8]
__device__ inline size_t pk256(int row, int k) {
    return ((size_t)((row >> 4) * 8 + (k >> 5))) * 512
         + (size_t)((((k >> 3) & 3) * 16 + (row & 15)) * 8 + (k & 7));
}
// V pack: (batch, token n, embed e) -> B-frag linear
__device__ inline size_t vpk_idx(int bb, int nn, int e) {
    return ((size_t)(bb*64 + (nn >> 5)) * 16 + (e >> 4)) * 512
         + (size_t)((((nn >> 3) & 3) * 16 + (e & 15)) * 8 + (nn & 7));
}

// ---------------- weight prep: transpose + cast + frag-pack ----------------
__global__ __launch_bounds__(256) void wprep_k(
    const float* __restrict__ Wq, const float* __restrict__ Wk,
    const float* __restrict__ Wv, const float* __restrict__ W1,
    const float* __restrict__ W2,
    ushort* __restrict__ WQKt, ushort* __restrict__ WVt,
    ushort* __restrict__ W1t, ushort* __restrict__ W2t)
{
    int id = blockIdx.x;          // 320 = 20 matrices x 16 tiles
    int m = id >> 4, t = id & 15;
    int l = m / 5, which = m % 5;
    const float* src; ushort* dst;
    size_t o = (size_t)l * 65536;
    switch (which) {
        case 0: src = Wq + o; dst = WQKt + (size_t)l*131072;          break;
        case 1: src = Wk + o; dst = WQKt + (size_t)l*131072 + 65536;  break;
        case 2: src = Wv + o; dst = WVt + o; break;
        case 3: src = W1 + o; dst = W1t + o; break;
        default: src = W2 + o; dst = W2t + o; break;
    }
    int tk = (t >> 2) * 64;   // k block
    int tn = (t & 3) * 64;    // n block (output col)
    __shared__ ushort T[64][68];
    int tid = threadIdx.x;
    int r = tid >> 4, c4 = (tid & 15) * 4;
    #pragma unroll
    for (int it = 0; it < 4; ++it) {
        int k = r + it*16;
        float4 v = *(const float4*)&src[(size_t)(tk + k)*256 + tn + c4];
        T[k][c4+0] = f2b(v.x); T[k][c4+1] = f2b(v.y);
        T[k][c4+2] = f2b(v.z); T[k][c4+3] = f2b(v.w);
    }
    __syncthreads();
    #pragma unroll
    for (int it = 0; it < 4; ++it) {
        int n = tn + r + it*16;
        int k0 = tk + c4;
        ushort4 ov;
        ov.x = T[c4+0][n-tn]; ov.y = T[c4+1][n-tn];
        ov.z = T[c4+2][n-tn]; ov.w = T[c4+3][n-tn];
        *(ushort4*)&dst[pk256(n, k0)] = ov;
    }
}

// ---------------- per-batch even-row base vector ----------------
__global__ __launch_bounds__(256) void base_even_k(
    const float* __restrict__ aset, const float* __restrict__ We,
    const float* __restrict__ be, float* __restrict__ BE)
{
    int b = blockIdx.x; int e = threadIdx.x;
    __shared__ float as[640];
    for (int i = e; i < 640; i += 256) as[i] = aset[b*640 + i];
    __syncthreads();
    float s = We[651*EE + e] + be[e];
    for (int f = 0; f < 640; ++f) s = fmaf(as[f], We[f*EE + e], s);
    BE[b*EE + e] = s;
}

// ---------------- embedding (8 rows per block), fp32 + packed bf16 ----------
__global__ __launch_bounds__(256) void embed_k(
    const float* __restrict__ BE, const float* __restrict__ ca,
    const float* __restrict__ cr, const float* __restrict__ We,
    const float* __restrict__ be, const float* __restrict__ wpe,
    float* __restrict__ H, ushort* __restrict__ Hbf)
{
    int e = threadIdx.x;
    #pragma unroll
    for (int k = 0; k < 8; ++k) {
        int rb = blockIdx.x * 8 + k;
        int b = rb >> 11, n = rb & (NN-1);
        float h;
        if ((n & 1) == 0) {
            h = BE[b*EE + e];
        } else {
            int t = n >> 1;
            h = We[651*EE + e] + be[e];
            const float* cap = ca + (size_t)(b*TT + t)*10;
            #pragma unroll
            for (int i = 0; i < 10; ++i) h = fmaf(cap[i], We[(640+i)*EE + e], h);
            h = fmaf(cr[b*TT + t], We[650*EE + e], h);
        }
        h = fmaf((float)(n + 1), We[652*EE + e], h);
        h += wpe[(size_t)n*EE + e];
        H[(size_t)rb*EE + e] = h;
        Hbf[pk256(rb, e)] = f2b(h);
    }
}

// ---------------- merged QKV GEMM (packed in, packed out) -------------------
__global__ __launch_bounds__(256, 2) void qkv_k(
    const ushort* __restrict__ A, const ushort* __restrict__ WQK,
    const ushort* __restrict__ WV,
    ushort* __restrict__ Qo, ushort* __restrict__ Ko, ushort* __restrict__ Vo)
{
    int tid = threadIdx.x;
    int w = tid >> 6, l = tid & 63;
    int lr = l & 15, lg = l >> 4;
    int wr = w >> 1, wc = w & 1;
    int rt0 = blockIdx.x * 8 + wr*4;
    int ct0 = blockIdx.y * 8 + wc*4;
    const ushort* Ap = A + (size_t)rt0*4096 + l*8;
    const ushort* Bp = (blockIdx.y < 4 ? WQK + (size_t)ct0*4096
                                       : WV + (size_t)(ct0-32)*4096) + l*8;
    f32x4 acc[4][4];
    #pragma unroll
    for (int i = 0; i < 4; ++i)
        #pragma unroll
        for (int j = 0; j < 4; ++j) acc[i][j] = (f32x4){0.f,0.f,0.f,0.f};
    #pragma unroll
    for (int kc = 0; kc < 8; ++kc) {
        short8 af[4], bf[4];
        #pragma unroll
        for (int rg = 0; rg < 4; ++rg) af[rg] = *(const short8*)(Ap + (size_t)rg*4096 + kc*512);
        #pragma unroll
        for (int cg = 0; cg < 4; ++cg) bf[cg] = *(const short8*)(Bp + (size_t)cg*4096 + kc*512);
        #pragma unroll
        for (int rg = 0; rg < 4; ++rg)
            #pragma unroll
            for (int cg = 0; cg < 4; ++cg)
                acc[rg][cg] = __builtin_amdgcn_mfma_f32_16x16x32_bf16(af[rg], bf[cg], acc[rg][cg], 0,0,0);
    }
    #pragma unroll
    for (int rg = 0; rg < 4; ++rg)
        #pragma unroll
        for (int cg = 0; cg < 4; ++cg)
            #pragma unroll
            for (int r = 0; r < 4; ++r) {
                int row = rt0*16 + rg*16 + lg*4 + r;
                int col = ct0*16 + cg*16 + lr;
                ushort xv = f2b(acc[rg][cg][r]);
                if (col < 256)      Qo[pk256(row, col)] = xv;
                else if (col < 512) Ko[pk256(row, col - 256)] = xv;
                else {
                    int e = col - 512, bb = row >> 11, nn = row & (NN-1);
                    Vo[vpk_idx(bb, nn, e)] = xv;
                }
            }
}

// ---------------- attention + ln1 + mlp1 + mlp2 + ln2 (full layer tail) -----
// EVEN=0: 512 blocks, slices of 16 consecutive rows (s=0..127 per batch).
// EVEN=1 (last layer): 256 blocks, wave covers the 16 EVEN rows of a 32-row
// window (s=0..63); odd rows are dead (preds read rows 0::2 only).
template<int EVEN>
__global__ __launch_bounds__(512, 2) void attn_k(
    const ushort* Qp, const ushort* __restrict__ Kp,
    const ushort* __restrict__ Vp, const float* H,
    const float* __restrict__ g, const float* __restrict__ bt,
    const ushort* __restrict__ W1t, const float* __restrict__ b1p,
    const ushort* __restrict__ W2t, const float* __restrict__ b2p,
    const float* __restrict__ g2, const float* __restrict__ bt2,
    float* Hout, ushort* __restrict__ Hpk)
{
    const int SMAX = EVEN ? 63 : 127;
    const int RS   = EVEN ? 2 : 1;
    int blk = blockIdx.x;            // pk*8 + b
    int pk = blk >> 3, b = blk & 7;
    int tid = threadIdx.x;
    int w = tid >> 6, l = tid & 63;
    int lr = l & 15, lg = l >> 4;
    int sel  = (w & 1) ^ ((w >> 2) & 1);
    int part = w >> 1;
    int s  = sel ? (SMAX - pk) : pk;         // slice index within batch
    int i0 = EVEN ? s*32 : s*16;             // base physical row
    int NT = EVEN ? (s + 1) : ((s >> 1) + 1); // causal j-tiles of 32
    int j0 = (part * NT) >> 2;
    int j1 = ((part + 1) * NT) >> 2;

    __shared__ float comb[2][5440];      // 43.5 KB: combine, then y fp32
    __shared__ ushort ylds[2][4096];     // 16 KB: y frags, then mid frags
    __shared__ float red2[2][16][4][2];  // 1 KB: ln2 cross-wave stats

    const ushort* Kbase = Kp + (size_t)(b*128) * 4096 + l*8;
    const ushort* Vbase = Vp + (size_t)(b*64) * 16 * 512 + l*8;

    // Q rows: lane lr -> physical row i0 + RS*lr (gathered when EVEN)
    short8 qb[8];
    {
        const ushort* Qb0 = Qp + (size_t)(b*128) * 4096;
        int qrow = i0 + RS*lr;
        #pragma unroll
        for (int kc = 0; kc < 8; ++kc)
            qb[kc] = *(const short8*)&Qb0[pk256(qrow, kc*32 + lg*8)];
    }

    f32x4 oacc[16];
    #pragma unroll
    for (int et = 0; et < 16; ++et) oacc[et] = (f32x4){0.f,0.f,0.f,0.f};

    int ig = i0 + RS*lr;
    for (int jt = j0; jt < j1; ++jt) {
        const ushort* Kt = Kbase + (size_t)(jt*2) * 4096;
        short8 ka0[8], ka1[8];
        #pragma unroll
        for (int kc = 0; kc < 8; ++kc) {
            ka0[kc] = *(const short8*)(Kt + kc*512);
            ka1[kc] = *(const short8*)(Kt + 4096 + kc*512);
        }
        const ushort* Vt = Vbase + (size_t)(jt*16) * 512;
        short8 vf[16];
        #pragma unroll
        for (int et = 0; et < 16; ++et)
            vf[et] = *(const short8*)(Vt + et*512);
        // QK^T (swapped), 4 independent chains
        f32x4 c0a = {0.f,0.f,0.f,0.f}, c0b = {0.f,0.f,0.f,0.f};
        f32x4 c1a = {0.f,0.f,0.f,0.f}, c1b = {0.f,0.f,0.f,0.f};
        #pragma unroll
        for (int kc = 0; kc < 8; kc += 2) {
            c0a = __builtin_amdgcn_mfma_f32_16x16x32_bf16(ka0[kc],   qb[kc],   c0a, 0,0,0);
            c0b = __builtin_amdgcn_mfma_f32_16x16x32_bf16(ka0[kc+1], qb[kc+1], c0b, 0,0,0);
            c1a = __builtin_amdgcn_mfma_f32_16x16x32_bf16(ka1[kc],   qb[kc],   c1a, 0,0,0);
            c1b = __builtin_amdgcn_mfma_f32_16x16x32_bf16(ka1[kc+1], qb[kc+1], c1b, 0,0,0);
        }
        f32x4 c0 = c0a + c0b, c1 = c1a + c1b;
        // relu + causal mask (j <= i)
        #pragma unroll
        for (int r = 0; r < 4; ++r) {
            int jg = jt*32 + lg*4 + r;
            c0[r] = (jg <= ig) ? fmaxf(c0[r], 0.f) : 0.f;
            c1[r] = (jg + 16 <= ig) ? fmaxf(c1[r], 0.f) : 0.f;
        }
        // pack to bf16 pairs and repack C-layout -> PV A-frag via shfl
        unsigned u0 = cvtpk(c0[0], c0[1]), u1 = cvtpk(c0[2], c0[3]);
        unsigned u2 = cvtpk(c1[0], c1[1]), u3 = cvtpk(c1[2], c1[3]);
        int srcA = 32*(lg & 1) + lr;
        int srcB = srcA + 16;
        unsigned a0A = __shfl((int)u0, srcA), a1A = __shfl((int)u1, srcA);
        unsigned a0B = __shfl((int)u0, srcB), a1B = __shfl((int)u1, srcB);
        unsigned b0A = __shfl((int)u2, srcA), b1A = __shfl((int)u3, srcA);
        unsigned b0B = __shfl((int)u2, srcB), b1B = __shfl((int)u3, srcB);
        bool lo = (lg < 2);
        union { unsigned u[4]; short8 v; } sv;
        sv.u[0] = lo ? a0A : b0A;
        sv.u[1] = lo ? a1A : b1A;
        sv.u[2] = lo ? a0B : b0B;
        sv.u[3] = lo ? a1B : b1B;
        short8 sa = sv.v;
        // PV: O[16][256] += S @ V_jt
        __builtin_amdgcn_s_setprio(1);
        #pragma unroll
        for (int et = 0; et < 16; ++et)
            oacc[et] = __builtin_amdgcn_mfma_f32_16x16x32_bf16(sa, vf[et], oacc[et], 0,0,0);
        __builtin_amdgcn_s_setprio(0);
    }

    // ---- 4-way combine (parts 1..3 -> LDS) ----
    float* cb = &comb[sel][0];
    #pragma unroll
    for (int rnd = 1; rnd <= 3; ++rnd) {
        if (part == rnd) {
            #pragma unroll
            for (int et = 0; et < 16; ++et)
                #pragma unroll
                for (int r = 0; r < 4; ++r) {
                    int idx = et*340 + l*5 + r;
                    float v = oacc[et][r];
                    if (rnd == 1) cb[idx] = v; else cb[idx] += v;
                }
        }
        __syncthreads();
    }
    // ---- epilogue by part 0: residual + scale + LN1 -> comb(y fp32) + ylds --
    if (part == 0) {
        float sm[4] = {0.f,0.f,0.f,0.f}, sq[4] = {0.f,0.f,0.f,0.f};
        #pragma unroll
        for (int et = 0; et < 16; ++et)
            #pragma unroll
            for (int r = 0; r < 4; ++r) {
                int irow = i0 + RS*(lg*4 + r);
                size_t base = ((size_t)(b*NN + irow))*EE + et*16 + lr;
                float x = H[base] + (oacc[et][r] + cb[et*340 + l*5 + r])
                                    * (1.0f / (float)(irow + 1));
                oacc[et][r] = x;
                sm[r] += x; sq[r] += x*x;
            }
        #pragma unroll
        for (int off = 1; off < 16; off <<= 1)
            #pragma unroll
            for (int r = 0; r < 4; ++r) {
                sm[r] += __shfl_xor(sm[r], off);
                sq[r] += __shfl_xor(sq[r], off);
            }
        float mean[4], inv[4];
        #pragma unroll
        for (int r = 0; r < 4; ++r) {
            mean[r] = sm[r] * (1.0f/256.0f);
            float var = sq[r] * (1.0f/256.0f) - mean[r]*mean[r];
            inv[r] = 1.0f / sqrtf(var + 1e-5f);
        }
        ushort* yl = &ylds[sel][0];
        #pragma unroll
        for (int et = 0; et < 16; ++et) {
            int col = et*16 + lr;
            float gv = g[col], bv = bt[col];
            #pragma unroll
            for (int r = 0; r < 4; ++r) {
                int row16 = lg*4 + r;
                float y = (oacc[et][r] - mean[r]) * inv[r] * gv + bv;
                cb[row16*YST + col] = y;   // y fp32 (comb region, now dead)
                int idx = (col >> 5)*512 + ((((col >> 3) & 3) << 4) + row16)*8
                        + (col & 7);
                yl[idx] = f2b(y);
            }
        }
    }
    __syncthreads();
    // ---- mlp1: all 8 waves; wave = (slice sel, 64-col group part) ----
    f32x4 macc[4];
    {
        const ushort* Ay = &ylds[sel][0] + l*8;
        const ushort* Bp = W1t + (size_t)(part*4)*4096 + l*8;
        #pragma unroll
        for (int cg = 0; cg < 4; ++cg) macc[cg] = (f32x4){0.f,0.f,0.f,0.f};
        #pragma unroll
        for (int kc = 0; kc < 8; ++kc) {
            short8 af = *(const short8*)(Ay + kc*512);
            #pragma unroll
            for (int cg = 0; cg < 4; ++cg) {
                short8 bf = *(const short8*)(Bp + (size_t)cg*4096 + kc*512);
                macc[cg] = __builtin_amdgcn_mfma_f32_16x16x32_bf16(af, bf, macc[cg], 0,0,0);
            }
        }
    }
    __syncthreads();   // all ylds (y-frag) reads complete
    // ---- write mid frags into ylds (overwrite) ----
    {
        ushort* yl = &ylds[sel][0];
        #pragma unroll
        for (int cg = 0; cg < 4; ++cg)
            #pragma unroll
            for (int r = 0; r < 4; ++r) {
                int col = part*64 + cg*16 + lr;
                int row16 = lg*4 + r;
                float x = fmaxf(macc[cg][r] + b1p[col], 0.f);
                int idx = (col >> 5)*512 + ((((col >> 3) & 3) << 4) + row16)*8
                        + (col & 7);
                yl[idx] = f2b(x);
            }
    }
    __syncthreads();
    // ---- mlp2 + b2 + y-residual, then ln2 ----
    float x2[4][4];
    {
        const ushort* Am = &ylds[sel][0] + l*8;
        const ushort* Bp = W2t + (size_t)(part*4)*4096 + l*8;
        f32x4 m2[4];
        #pragma unroll
        for (int cg = 0; cg < 4; ++cg) m2[cg] = (f32x4){0.f,0.f,0.f,0.f};
        #pragma unroll
        for (int kc = 0; kc < 8; ++kc) {
            short8 af = *(const short8*)(Am + kc*512);
            #pragma unroll
            for (int cg = 0; cg < 4; ++cg) {
                short8 bf = *(const short8*)(Bp + (size_t)cg*4096 + kc*512);
                m2[cg] = __builtin_amdgcn_mfma_f32_16x16x32_bf16(af, bf, m2[cg], 0,0,0);
            }
        }
        float sm2[4] = {0.f,0.f,0.f,0.f}, sq2[4] = {0.f,0.f,0.f,0.f};
        #pragma unroll
        for (int cg = 0; cg < 4; ++cg)
            #pragma unroll
            for (int r = 0; r < 4; ++r) {
                int col = part*64 + cg*16 + lr;
                int row16 = lg*4 + r;
                float v = m2[cg][r] + b2p[col] + cb[row16*YST + col];
                x2[cg][r] = v;
                sm2[r] += v; sq2[r] += v*v;
            }
        #pragma unroll
        for (int off = 1; off < 16; off <<= 1)
            #pragma unroll
            for (int r = 0; r < 4; ++r) {
                sm2[r] += __shfl_xor(sm2[r], off);
                sq2[r] += __shfl_xor(sq2[r], off);
            }
        if (lr == 0) {
            #pragma unroll
            for (int r = 0; r < 4; ++r) {
                red2[sel][lg*4 + r][part][0] = sm2[r];
                red2[sel][lg*4 + r][part][1] = sq2[r];
            }
        }
    }
    __syncthreads();
    {
        float mean[4], inv[4];
        #pragma unroll
        for (int r = 0; r < 4; ++r) {
            int row16 = lg*4 + r;
            float S  = red2[sel][row16][0][0] + red2[sel][row16][1][0]
                     + red2[sel][row16][2][0] + red2[sel][row16][3][0];
            float S2 = red2[sel][row16][0][1] + red2[sel][row16][1][1]
                     + red2[sel][row16][2][1] + red2[sel][row16][3][1];
            mean[r] = S * (1.0f/256.0f);
            float var = S2 * (1.0f/256.0f) - mean[r]*mean[r];
            inv[r] = 1.0f / sqrtf(var + 1e-5f);
        }
        #pragma unroll
        for (int cg = 0; cg < 4; ++cg) {
            int col = part*64 + cg*16 + lr;
            float gv = g2[col], bv = bt2[col];
            #pragma unroll
            for (int r = 0; r < 4; ++r) {
                int irow = i0 + RS*(lg*4 + r);
                size_t base = ((size_t)(b*NN + irow))*EE + col;
                float y2 = (x2[cg][r] - mean[r]) * inv[r] * gv + bv;
                Hout[base] = y2;
                Hpk[pk256(b*NN + irow, col)] = f2b(y2);
            }
        }
    }
}

// ---------------- prediction head (even rows only) ----------------
__global__ __launch_bounds__(256) void pred_k(
    const float* __restrict__ H, const float* __restrict__ Wp,
    const float* __restrict__ bp, float* __restrict__ out)
{
    int bt = blockIdx.x;
    int b = bt >> 10, t = bt & 1023;
    size_t row = (size_t)b*NN + 2*t;
    __shared__ float hs[256];
    __shared__ float pr[16][16];
    int tid = threadIdx.x;
    hs[tid] = H[row*EE + tid];
    __syncthreads();
    int c = tid & 15, seg = tid >> 4;
    float p = 0.f;
    if (c < 10) {
        #pragma unroll
        for (int e2 = 0; e2 < 16; ++e2)
            p = fmaf(hs[seg*16 + e2], Wp[(seg*16 + e2)*10 + c], p);
    }
    pr[seg][c] = p;
    __syncthreads();
    if (tid < 10) {
        float sacc = bp[tid];
        #pragma unroll
        for (int k2 = 0; k2 < 16; ++k2) sacc += pr[k2][tid];
        out[(size_t)bt*10 + tid] = sacc;
    }
}

extern "C" void kernel_launch(void* const* d_in, const int* in_sizes, int n_in,
                              void* d_out, int out_size, void* d_ws, size_t ws_size,
                              hipStream_t stream)
{
    const float* action_set = (const float*)d_in[1];
    const float* ctx_act    = (const float*)d_in[2];
    const float* ctx_rew    = (const float*)d_in[3];
    const float* W_embed    = (const float*)d_in[4];
    const float* b_embed    = (const float*)d_in[5];
    const float* wpe        = (const float*)d_in[6];
    const float* Wq         = (const float*)d_in[7];
    const float* Wk         = (const float*)d_in[8];
    const float* Wv         = (const float*)d_in[9];
    const float* ln1g       = (const float*)d_in[10];
    const float* ln1b       = (const float*)d_in[11];
    const float* W1         = (const float*)d_in[12];
    const float* b1         = (const float*)d_in[13];
    const float* W2         = (const float*)d_in[14];
    const float* b2         = (const float*)d_in[15];
    const float* ln2g       = (const float*)d_in[16];
    const float* ln2b       = (const float*)d_in[17];
    const float* Wp         = (const float*)d_in[18];
    const float* bp         = (const float*)d_in[19];
    float* out = (float*)d_out;

    float* ws = (float*)d_ws;
    const size_t SZ = (size_t)BB*NN*EE;   // 4,194,304
    size_t o = 0;
    float*  Hb   = ws;               o += SZ;        // fp32 residual stream (in/out)
    ushort* Hbf  = (ushort*)(ws+o);  o += SZ/2;      // packed bf16 stream
    ushort* Qp   = (ushort*)(ws+o);  o += SZ/2;      // packed Q
    ushort* Kpk  = (ushort*)(ws+o);  o += SZ/2;      // packed K
    ushort* Vpk  = (ushort*)(ws+o);  o += SZ/2;      // packed V
    ushort* WQKt = (ushort*)(ws+o);  o += 262144;
    ushort* WVt  = (ushort*)(ws+o);  o += 131072;
    ushort* W1t  = (ushort*)(ws+o);  o += 131072;
    ushort* W2t  = (ushort*)(ws+o);  o += 131072;
    float*  BE   = ws + o;

    wprep_k<<<320, 256, 0, stream>>>(Wq, Wk, Wv, W1, W2, WQKt, WVt, W1t, W2t);
    base_even_k<<<BB, 256, 0, stream>>>(action_set, W_embed, b_embed, BE);
    embed_k<<<BB*NN/8, 256, 0, stream>>>(BE, ctx_act, ctx_rew, W_embed, b_embed, wpe, Hb, Hbf);

    for (int l = 0; l < LL; ++l) {
        qkv_k<<<dim3(128, 6), 256, 0, stream>>>(
            Hbf, WQKt + (size_t)l*131072, WVt + (size_t)l*65536, Qp, Kpk, Vpk);
        // full layer tail: attn + ln1 + mlp1 + mlp2 + ln2 -> Hb, Hbf (in-place)
        if (l < LL-1) {
            attn_k<0><<<512, 512, 0, stream>>>(
                Qp, Kpk, Vpk, Hb, ln1g + l*EE, ln1b + l*EE,
                W1t + (size_t)l*65536, b1 + l*EE,
                W2t + (size_t)l*65536, b2 + l*EE,
                ln2g + l*EE, ln2b + l*EE, Hb, Hbf);
        } else {
            // last layer: only even rows are observable (preds = rows 0::2)
            attn_k<1><<<256, 512, 0, stream>>>(
                Qp, Kpk, Vpk, Hb, ln1g + l*EE, ln1b + l*EE,
                W1t + (size_t)l*65536, b1 + l*EE,
                W2t + (size_t)l*65536, b2 + l*EE,
                ln2g + l*EE, ln2b + l*EE, Hb, Hbf);
        }
    }
    pred_k<<<BB*TT, 256, 0, stream>>>(Hb, Wp, bp, out);
}

// Round 17
// 363.526 us; speedup vs baseline: 1.0433x; 1.0153x over previous
//
#include <hip/hip_runtime.h>

// Transformer_67748814127473 — round 16: R13/R15 base + pred fused into the
// last layer's tail (attn_k<1> computes preds directly from in-register y2;
// pred_k and last-layer Hout/Hpk stores deleted).
// B=8, T=1024, N=2048, E=256, L=4.

#define BB 8
#define TT 1024
#define NN 2048
#define EE 256
#define LL 4
#define YST 258   // y fp32 LDS stride

typedef __attribute__((ext_vector_type(8))) short short8;
typedef __attribute__((ext_vector_type(4))) float f32x4;

__device__ inline ushort f2b(float f) {
    union { float f; unsigned u; } x; x.f = f;
    unsigned u = x.u;
    return (ushort)((u + 0x7fffu + ((u >> 16) & 1u)) >> 16);
}
__device__ inline unsigned cvtpk(float lo, float hi) {
    unsigned r;
    asm volatile("v_cvt_pk_bf16_f32 %0, %1, %2" : "=v"(r) : "v"(lo), "v"(hi));
    return r;
}
// fragment-linear pack for K=256 operands: tile16(row) x kchunk32 -> [lane][8]
__device__ inline size_t pk256(int row, int k) {
    return ((size_t)((row >> 4) * 8 + (k >> 5))) * 512
         + (size_t)((((k >> 3) & 3) * 16 + (row & 15)) * 8 + (k & 7));
}
// V pack: (batch, token n, embed e) -> B-frag linear
__device__ inline size_t vpk_idx(int bb, int nn, int e) {
    return ((size_t)(bb*64 + (nn >> 5)) * 16 + (e >> 4)) * 512
         + (size_t)((((nn >> 3) & 3) * 16 + (e & 15)) * 8 + (nn & 7));
}

// ---------------- weight prep: transpose + cast + frag-pack ----------------
__global__ __launch_bounds__(256) void wprep_k(
    const float* __restrict__ Wq, const float* __restrict__ Wk,
    const float* __restrict__ Wv, const float* __restrict__ W1,
    const float* __restrict__ W2,
    ushort* __restrict__ WQKt, ushort* __restrict__ WVt,
    ushort* __restrict__ W1t, ushort* __restrict__ W2t)
{
    int id = blockIdx.x;          // 320 = 20 matrices x 16 tiles
    int m = id >> 4, t = id & 15;
    int l = m / 5, which = m % 5;
    const float* src; ushort* dst;
    size_t o = (size_t)l * 65536;
    switch (which) {
        case 0: src = Wq + o; dst = WQKt + (size_t)l*131072;          break;
        case 1: src = Wk + o; dst = WQKt + (size_t)l*131072 + 65536;  break;
        case 2: src = Wv + o; dst = WVt + o; break;
        case 3: src = W1 + o; dst = W1t + o; break;
        default: src = W2 + o; dst = W2t + o; break;
    }
    int tk = (t >> 2) * 64;   // k block
    int tn = (t & 3) * 64;    // n block (output col)
    __shared__ ushort T[64][68];
    int tid = threadIdx.x;
    int r = tid >> 4, c4 = (tid & 15) * 4;
    #pragma unroll
    for (int it = 0; it < 4; ++it) {
        int k = r + it*16;
        float4 v = *(const float4*)&src[(size_t)(tk + k)*256 + tn + c4];
        T[k][c4+0] = f2b(v.x); T[k][c4+1] = f2b(v.y);
        T[k][c4+2] = f2b(v.z); T[k][c4+3] = f2b(v.w);
    }
    __syncthreads();
    #pragma unroll
    for (int it = 0; it < 4; ++it) {
        int n = tn + r + it*16;
        int k0 = tk + c4;
        ushort4 ov;
        ov.x = T[c4+0][n-tn]; ov.y = T[c4+1][n-tn];
        ov.z = T[c4+2][n-tn]; ov.w = T[c4+3][n-tn];
        *(ushort4*)&dst[pk256(n, k0)] = ov;
    }
}

// ---------------- per-batch even-row base vector ----------------
__global__ __launch_bounds__(256) void base_even_k(
    const float* __restrict__ aset, const float* __restrict__ We,
    const float* __restrict__ be, float* __restrict__ BE)
{
    int b = blockIdx.x; int e = threadIdx.x;
    __shared__ float as[640];
    for (int i = e; i < 640; i += 256) as[i] = aset[b*640 + i];
    __syncthreads();
    float s = We[651*EE + e] + be[e];
    for (int f = 0; f < 640; ++f) s = fmaf(as[f], We[f*EE + e], s);
    BE[b*EE + e] = s;
}

// ---------------- embedding (8 rows per block), fp32 + packed bf16 ----------
__global__ __launch_bounds__(256) void embed_k(
    const float* __restrict__ BE, const float* __restrict__ ca,
    const float* __restrict__ cr, const float* __restrict__ We,
    const float* __restrict__ be, const float* __restrict__ wpe,
    float* __restrict__ H, ushort* __restrict__ Hbf)
{
    int e = threadIdx.x;
    #pragma unroll
    for (int k = 0; k < 8; ++k) {
        int rb = blockIdx.x * 8 + k;
        int b = rb >> 11, n = rb & (NN-1);
        float h;
        if ((n & 1) == 0) {
            h = BE[b*EE + e];
        } else {
            int t = n >> 1;
            h = We[651*EE + e] + be[e];
            const float* cap = ca + (size_t)(b*TT + t)*10;
            #pragma unroll
            for (int i = 0; i < 10; ++i) h = fmaf(cap[i], We[(640+i)*EE + e], h);
            h = fmaf(cr[b*TT + t], We[650*EE + e], h);
        }
        h = fmaf((float)(n + 1), We[652*EE + e], h);
        h += wpe[(size_t)n*EE + e];
        H[(size_t)rb*EE + e] = h;
        Hbf[pk256(rb, e)] = f2b(h);
    }
}

// ---------------- merged QKV GEMM (packed in, packed out) -------------------
__global__ __launch_bounds__(256, 2) void qkv_k(
    const ushort* __restrict__ A, const ushort* __restrict__ WQK,
    const ushort* __restrict__ WV,
    ushort* __restrict__ Qo, ushort* __restrict__ Ko, ushort* __restrict__ Vo)
{
    int tid = threadIdx.x;
    int w = tid >> 6, l = tid & 63;
    int lr = l & 15, lg = l >> 4;
    int wr = w >> 1, wc = w & 1;
    int rt0 = blockIdx.x * 8 + wr*4;
    int ct0 = blockIdx.y * 8 + wc*4;
    const ushort* Ap = A + (size_t)rt0*4096 + l*8;
    const ushort* Bp = (blockIdx.y < 4 ? WQK + (size_t)ct0*4096
                                       : WV + (size_t)(ct0-32)*4096) + l*8;
    f32x4 acc[4][4];
    #pragma unroll
    for (int i = 0; i < 4; ++i)
        #pragma unroll
        for (int j = 0; j < 4; ++j) acc[i][j] = (f32x4){0.f,0.f,0.f,0.f};
    #pragma unroll
    for (int kc = 0; kc < 8; ++kc) {
        short8 af[4], bf[4];
        #pragma unroll
        for (int rg = 0; rg < 4; ++rg) af[rg] = *(const short8*)(Ap + (size_t)rg*4096 + kc*512);
        #pragma unroll
        for (int cg = 0; cg < 4; ++cg) bf[cg] = *(const short8*)(Bp + (size_t)cg*4096 + kc*512);
        #pragma unroll
        for (int rg = 0; rg < 4; ++rg)
            #pragma unroll
            for (int cg = 0; cg < 4; ++cg)
                acc[rg][cg] = __builtin_amdgcn_mfma_f32_16x16x32_bf16(af[rg], bf[cg], acc[rg][cg], 0,0,0);
    }
    #pragma unroll
    for (int rg = 0; rg < 4; ++rg)
        #pragma unroll
        for (int cg = 0; cg < 4; ++cg)
            #pragma unroll
            for (int r = 0; r < 4; ++r) {
                int row = rt0*16 + rg*16 + lg*4 + r;
                int col = ct0*16 + cg*16 + lr;
                ushort xv = f2b(acc[rg][cg][r]);
                if (col < 256)      Qo[pk256(row, col)] = xv;
                else if (col < 512) Ko[pk256(row, col - 256)] = xv;
                else {
                    int e = col - 512, bb = row >> 11, nn = row & (NN-1);
                    Vo[vpk_idx(bb, nn, e)] = xv;
                }
            }
}

// ---------------- attention + ln1 + mlp1 + mlp2 + ln2 (+ pred when EVEN) ----
// EVEN=0: 512 blocks, slices of 16 consecutive rows (s=0..127 per batch);
//         writes Hout fp32 + Hpk packed.
// EVEN=1 (last layer): 256 blocks, wave covers the 16 EVEN rows of a 32-row
//         window (s=0..63); instead of storing H, computes preds directly.
template<int EVEN>
__global__ __launch_bounds__(512, 2) void attn_k(
    const ushort* Qp, const ushort* __restrict__ Kp,
    const ushort* __restrict__ Vp, const float* H,
    const float* __restrict__ g, const float* __restrict__ bt,
    const ushort* __restrict__ W1t, const float* __restrict__ b1p,
    const ushort* __restrict__ W2t, const float* __restrict__ b2p,
    const float* __restrict__ g2, const float* __restrict__ bt2,
    float* Hout, ushort* __restrict__ Hpk,
    const float* __restrict__ Wp, const float* __restrict__ bp,
    float* __restrict__ out)
{
    const int SMAX = EVEN ? 63 : 127;
    const int RS   = EVEN ? 2 : 1;
    int blk = blockIdx.x;            // pk*8 + b
    int pk = blk >> 3, b = blk & 7;
    int tid = threadIdx.x;
    int w = tid >> 6, l = tid & 63;
    int lr = l & 15, lg = l >> 4;
    int sel  = (w & 1) ^ ((w >> 2) & 1);
    int part = w >> 1;
    int s  = sel ? (SMAX - pk) : pk;         // slice index within batch
    int i0 = EVEN ? s*32 : s*16;             // base physical row
    int NT = EVEN ? (s + 1) : ((s >> 1) + 1); // causal j-tiles of 32
    int j0 = (part * NT) >> 2;
    int j1 = ((part + 1) * NT) >> 2;

    __shared__ float comb[2][5440];      // 43.5 KB: combine, then y fp32
    __shared__ ushort ylds[2][4096];     // 16 KB: y frags, mid frags, pred red
    __shared__ float red2[2][16][4][2];  // 1 KB: ln2 cross-wave stats

    const ushort* Kbase = Kp + (size_t)(b*128) * 4096 + l*8;
    const ushort* Vbase = Vp + (size_t)(b*64) * 16 * 512 + l*8;

    // Q rows: lane lr -> physical row i0 + RS*lr (gathered when EVEN)
    short8 qb[8];
    {
        const ushort* Qb0 = Qp + (size_t)(b*128) * 4096;
        int qrow = i0 + RS*lr;
        #pragma unroll
        for (int kc = 0; kc < 8; ++kc)
            qb[kc] = *(const short8*)&Qb0[pk256(qrow, kc*32 + lg*8)];
    }

    f32x4 oacc[16];
    #pragma unroll
    for (int et = 0; et < 16; ++et) oacc[et] = (f32x4){0.f,0.f,0.f,0.f};

    int ig = i0 + RS*lr;
    for (int jt = j0; jt < j1; ++jt) {
        const ushort* Kt = Kbase + (size_t)(jt*2) * 4096;
        short8 ka0[8], ka1[8];
        #pragma unroll
        for (int kc = 0; kc < 8; ++kc) {
            ka0[kc] = *(const short8*)(Kt + kc*512);
            ka1[kc] = *(const short8*)(Kt + 4096 + kc*512);
        }
        const ushort* Vt = Vbase + (size_t)(jt*16) * 512;
        short8 vf[16];
        #pragma unroll
        for (int et = 0; et < 16; ++et)
            vf[et] = *(const short8*)(Vt + et*512);
        // QK^T (swapped), 4 independent chains
        f32x4 c0a = {0.f,0.f,0.f,0.f}, c0b = {0.f,0.f,0.f,0.f};
        f32x4 c1a = {0.f,0.f,0.f,0.f}, c1b = {0.f,0.f,0.f,0.f};
        #pragma unroll
        for (int kc = 0; kc < 8; kc += 2) {
            c0a = __builtin_amdgcn_mfma_f32_16x16x32_bf16(ka0[kc],   qb[kc],   c0a, 0,0,0);
            c0b = __builtin_amdgcn_mfma_f32_16x16x32_bf16(ka0[kc+1], qb[kc+1], c0b, 0,0,0);
            c1a = __builtin_amdgcn_mfma_f32_16x16x32_bf16(ka1[kc],   qb[kc],   c1a, 0,0,0);
            c1b = __builtin_amdgcn_mfma_f32_16x16x32_bf16(ka1[kc+1], qb[kc+1], c1b, 0,0,0);
        }
        f32x4 c0 = c0a + c0b, c1 = c1a + c1b;
        // relu + causal mask (j <= i)
        #pragma unroll
        for (int r = 0; r < 4; ++r) {
            int jg = jt*32 + lg*4 + r;
            c0[r] = (jg <= ig) ? fmaxf(c0[r], 0.f) : 0.f;
            c1[r] = (jg + 16 <= ig) ? fmaxf(c1[r], 0.f) : 0.f;
        }
        // pack to bf16 pairs and repack C-layout -> PV A-frag via shfl
        unsigned u0 = cvtpk(c0[0], c0[1]), u1 = cvtpk(c0[2], c0[3]);
        unsigned u2 = cvtpk(c1[0], c1[1]), u3 = cvtpk(c1[2], c1[3]);
        int srcA = 32*(lg & 1) + lr;
        int srcB = srcA + 16;
        unsigned a0A = __shfl((int)u0, srcA), a1A = __shfl((int)u1, srcA);
        unsigned a0B = __shfl((int)u0, srcB), a1B = __shfl((int)u1, srcB);
        unsigned b0A = __shfl((int)u2, srcA), b1A = __shfl((int)u3, srcA);
        unsigned b0B = __shfl((int)u2, srcB), b1B = __shfl((int)u3, srcB);
        bool lo = (lg < 2);
        union { unsigned u[4]; short8 v; } sv;
        sv.u[0] = lo ? a0A : b0A;
        sv.u[1] = lo ? a1A : b1A;
        sv.u[2] = lo ? a0B : b0B;
        sv.u[3] = lo ? a1B : b1B;
        short8 sa = sv.v;
        // PV: O[16][256] += S @ V_jt
        __builtin_amdgcn_s_setprio(1);
        #pragma unroll
        for (int et = 0; et < 16; ++et)
            oacc[et] = __builtin_amdgcn_mfma_f32_16x16x32_bf16(sa, vf[et], oacc[et], 0,0,0);
        __builtin_amdgcn_s_setprio(0);
    }

    // ---- 4-way combine (parts 1..3 -> LDS) ----
    float* cb = &comb[sel][0];
    #pragma unroll
    for (int rnd = 1; rnd <= 3; ++rnd) {
        if (part == rnd) {
            #pragma unroll
            for (int et = 0; et < 16; ++et)
                #pragma unroll
                for (int r = 0; r < 4; ++r) {
                    int idx = et*340 + l*5 + r;
                    float v = oacc[et][r];
                    if (rnd == 1) cb[idx] = v; else cb[idx] += v;
                }
        }
        __syncthreads();
    }
    // ---- epilogue by part 0: residual + scale + LN1 -> comb(y fp32) + ylds --
    if (part == 0) {
        float sm[4] = {0.f,0.f,0.f,0.f}, sq[4] = {0.f,0.f,0.f,0.f};
        #pragma unroll
        for (int et = 0; et < 16; ++et)
            #pragma unroll
            for (int r = 0; r < 4; ++r) {
                int irow = i0 + RS*(lg*4 + r);
                size_t base = ((size_t)(b*NN + irow))*EE + et*16 + lr;
                float x = H[base] + (oacc[et][r] + cb[et*340 + l*5 + r])
                                    * (1.0f / (float)(irow + 1));
                oacc[et][r] = x;
                sm[r] += x; sq[r] += x*x;
            }
        #pragma unroll
        for (int off = 1; off < 16; off <<= 1)
            #pragma unroll
            for (int r = 0; r < 4; ++r) {
                sm[r] += __shfl_xor(sm[r], off);
                sq[r] += __shfl_xor(sq[r], off);
            }
        float mean[4], inv[4];
        #pragma unroll
        for (int r = 0; r < 4; ++r) {
            mean[r] = sm[r] * (1.0f/256.0f);
            float var = sq[r] * (1.0f/256.0f) - mean[r]*mean[r];
            inv[r] = 1.0f / sqrtf(var + 1e-5f);
        }
        ushort* yl = &ylds[sel][0];
        #pragma unroll
        for (int et = 0; et < 16; ++et) {
            int col = et*16 + lr;
            float gv = g[col], bv = bt[col];
            #pragma unroll
            for (int r = 0; r < 4; ++r) {
                int row16 = lg*4 + r;
                float y = (oacc[et][r] - mean[r]) * inv[r] * gv + bv;
                cb[row16*YST + col] = y;   // y fp32 (comb region, now dead)
                int idx = (col >> 5)*512 + ((((col >> 3) & 3) << 4) + row16)*8
                        + (col & 7);
                yl[idx] = f2b(y);
            }
        }
    }
    __syncthreads();
    // ---- mlp1: all 8 waves; wave = (slice sel, 64-col group part) ----
    f32x4 macc[4];
    {
        const ushort* Ay = &ylds[sel][0] + l*8;
        const ushort* Bp = W1t + (size_t)(part*4)*4096 + l*8;
        #pragma unroll
        for (int cg = 0; cg < 4; ++cg) macc[cg] = (f32x4){0.f,0.f,0.f,0.f};
        #pragma unroll
        for (int kc = 0; kc < 8; ++kc) {
            short8 af = *(const short8*)(Ay + kc*512);
            #pragma unroll
            for (int cg = 0; cg < 4; ++cg) {
                short8 bf = *(const short8*)(Bp + (size_t)cg*4096 + kc*512);
                macc[cg] = __builtin_amdgcn_mfma_f32_16x16x32_bf16(af, bf, macc[cg], 0,0,0);
            }
        }
    }
    __syncthreads();   // all ylds (y-frag) reads complete
    // ---- write mid frags into ylds (overwrite) ----
    {
        ushort* yl = &ylds[sel][0];
        #pragma unroll
        for (int cg = 0; cg < 4; ++cg)
            #pragma unroll
            for (int r = 0; r < 4; ++r) {
                int col = part*64 + cg*16 + lr;
                int row16 = lg*4 + r;
                float x = fmaxf(macc[cg][r] + b1p[col], 0.f);
                int idx = (col >> 5)*512 + ((((col >> 3) & 3) << 4) + row16)*8
                        + (col & 7);
                yl[idx] = f2b(x);
            }
    }
    __syncthreads();
    // ---- mlp2 + b2 + y-residual, then ln2 ----
    float x2[4][4];
    {
        const ushort* Am = &ylds[sel][0] + l*8;
        const ushort* Bp = W2t + (size_t)(part*4)*4096 + l*8;
        f32x4 m2[4];
        #pragma unroll
        for (int cg = 0; cg < 4; ++cg) m2[cg] = (f32x4){0.f,0.f,0.f,0.f};
        #pragma unroll
        for (int kc = 0; kc < 8; ++kc) {
            short8 af = *(const short8*)(Am + kc*512);
            #pragma unroll
            for (int cg = 0; cg < 4; ++cg) {
                short8 bf = *(const short8*)(Bp + (size_t)cg*4096 + kc*512);
                m2[cg] = __builtin_amdgcn_mfma_f32_16x16x32_bf16(af, bf, m2[cg], 0,0,0);
            }
        }
        float sm2[4] = {0.f,0.f,0.f,0.f}, sq2[4] = {0.f,0.f,0.f,0.f};
        #pragma unroll
        for (int cg = 0; cg < 4; ++cg)
            #pragma unroll
            for (int r = 0; r < 4; ++r) {
                int col = part*64 + cg*16 + lr;
                int row16 = lg*4 + r;
                float v = m2[cg][r] + b2p[col] + cb[row16*YST + col];
                x2[cg][r] = v;
                sm2[r] += v; sq2[r] += v*v;
            }
        #pragma unroll
        for (int off = 1; off < 16; off <<= 1)
            #pragma unroll
            for (int r = 0; r < 4; ++r) {
                sm2[r] += __shfl_xor(sm2[r], off);
                sq2[r] += __shfl_xor(sq2[r], off);
            }
        if (lr == 0) {
            #pragma unroll
            for (int r = 0; r < 4; ++r) {
                red2[sel][lg*4 + r][part][0] = sm2[r];
                red2[sel][lg*4 + r][part][1] = sq2[r];
            }
        }
    }
    __syncthreads();
    {
        float mean[4], inv[4];
        #pragma unroll
        for (int r = 0; r < 4; ++r) {
            int row16 = lg*4 + r;
            float S  = red2[sel][row16][0][0] + red2[sel][row16][1][0]
                     + red2[sel][row16][2][0] + red2[sel][row16][3][0];
            float S2 = red2[sel][row16][0][1] + red2[sel][row16][1][1]
                     + red2[sel][row16][2][1] + red2[sel][row16][3][1];
            mean[r] = S * (1.0f/256.0f);
            float var = S2 * (1.0f/256.0f) - mean[r]*mean[r];
            inv[r] = 1.0f / sqrtf(var + 1e-5f);
        }
        if (!EVEN) {
            // intermediate layers: store H stream (fp32 + packed bf16)
            #pragma unroll
            for (int cg = 0; cg < 4; ++cg) {
                int col = part*64 + cg*16 + lr;
                float gv = g2[col], bv = bt2[col];
                #pragma unroll
                for (int r = 0; r < 4; ++r) {
                    int irow = i0 + RS*(lg*4 + r);
                    size_t base = ((size_t)(b*NN + irow))*EE + col;
                    float y2 = (x2[cg][r] - mean[r]) * inv[r] * gv + bv;
                    Hout[base] = y2;
                    Hpk[pk256(b*NN + irow, col)] = f2b(y2);
                }
            }
        } else {
            // last layer: preds = y2 @ Wp + bp, computed in-register.
            // thread partial over its 16 cols -> 16-lane shfl reduce ->
            // 4-part combine via ylds (dead) -> part-0 writes out.
            float pp[4][10];
            #pragma unroll
            for (int r = 0; r < 4; ++r)
                #pragma unroll
                for (int c = 0; c < 10; ++c) pp[r][c] = 0.f;
            #pragma unroll
            for (int cg = 0; cg < 4; ++cg) {
                int col = part*64 + cg*16 + lr;
                float gv = g2[col], bv = bt2[col];
                #pragma unroll
                for (int r = 0; r < 4; ++r) {
                    float y2 = (x2[cg][r] - mean[r]) * inv[r] * gv + bv;
                    #pragma unroll
                    for (int c = 0; c < 10; ++c)
                        pp[r][c] = fmaf(y2, Wp[col*10 + c], pp[r][c]);
                }
            }
            #pragma unroll
            for (int off = 1; off < 16; off <<= 1)
                #pragma unroll
                for (int r = 0; r < 4; ++r)
                    #pragma unroll
                    for (int c = 0; c < 10; ++c)
                        pp[r][c] += __shfl_xor(pp[r][c], off);
            float* redp = (float*)&ylds[0][0];   // 2*4*16*10*4B = 5.1KB <= 16KB
            if (lr == 0) {
                #pragma unroll
                for (int r = 0; r < 4; ++r)
                    #pragma unroll
                    for (int c = 0; c < 10; ++c)
                        redp[(((sel*4 + part)*16) + lg*4 + r)*10 + c] = pp[r][c];
            }
            __syncthreads();
            if (part == 0 && lr < 10) {
                #pragma unroll
                for (int r = 0; r < 4; ++r) {
                    int row16 = lg*4 + r;
                    float sacc = bp[lr];
                    #pragma unroll
                    for (int p2 = 0; p2 < 4; ++p2)
                        sacc += redp[(((sel*4 + p2)*16) + row16)*10 + lr];
                    int t_idx = (i0 >> 1) + row16;   // even row -> token index
                    out[((size_t)(b*TT + t_idx))*10 + lr] = sacc;
                }
            }
        }
    }
}

extern "C" void kernel_launch(void* const* d_in, const int* in_sizes, int n_in,
                              void* d_out, int out_size, void* d_ws, size_t ws_size,
                              hipStream_t stream)
{
    const float* action_set = (const float*)d_in[1];
    const float* ctx_act    = (const float*)d_in[2];
    const float* ctx_rew    = (const float*)d_in[3];
    const float* W_embed    = (const float*)d_in[4];
    const float* b_embed    = (const float*)d_in[5];
    const float* wpe        = (const float*)d_in[6];
    const float* Wq         = (const float*)d_in[7];
    const float* Wk         = (const float*)d_in[8];
    const float* Wv         = (const float*)d_in[9];
    const float* ln1g       = (const float*)d_in[10];
    const float* ln1b       = (const float*)d_in[11];
    const float* W1         = (const float*)d_in[12];
    const float* b1         = (const float*)d_in[13];
    const float* W2         = (const float*)d_in[14];
    const float* b2         = (const float*)d_in[15];
    const float* ln2g       = (const float*)d_in[16];
    const float* ln2b       = (const float*)d_in[17];
    const float* Wp         = (const float*)d_in[18];
    const float* bp         = (const float*)d_in[19];
    float* out = (float*)d_out;

    float* ws = (float*)d_ws;
    const size_t SZ = (size_t)BB*NN*EE;   // 4,194,304
    size_t o = 0;
    float*  Hb   = ws;               o += SZ;        // fp32 residual stream (in/out)
    ushort* Hbf  = (ushort*)(ws+o);  o += SZ/2;      // packed bf16 stream
    ushort* Qp   = (ushort*)(ws+o);  o += SZ/2;      // packed Q
    ushort* Kpk  = (ushort*)(ws+o);  o += SZ/2;      // packed K
    ushort* Vpk  = (ushort*)(ws+o);  o += SZ/2;      // packed V
    ushort* WQKt = (ushort*)(ws+o);  o += 262144;
    ushort* WVt  = (ushort*)(ws+o);  o += 131072;
    ushort* W1t  = (ushort*)(ws+o);  o += 131072;
    ushort* W2t  = (ushort*)(ws+o);  o += 131072;
    float*  BE   = ws + o;

    wprep_k<<<320, 256, 0, stream>>>(Wq, Wk, Wv, W1, W2, WQKt, WVt, W1t, W2t);
    base_even_k<<<BB, 256, 0, stream>>>(action_set, W_embed, b_embed, BE);
    embed_k<<<BB*NN/8, 256, 0, stream>>>(BE, ctx_act, ctx_rew, W_embed, b_embed, wpe, Hb, Hbf);

    for (int l = 0; l < LL; ++l) {
        qkv_k<<<dim3(128, 6), 256, 0, stream>>>(
            Hbf, WQKt + (size_t)l*131072, WVt + (size_t)l*65536, Qp, Kpk, Vpk);
        if (l < LL-1) {
            attn_k<0><<<512, 512, 0, stream>>>(
                Qp, Kpk, Vpk, Hb, ln1g + l*EE, ln1b + l*EE,
                W1t + (size_t)l*65536, b1 + l*EE,
                W2t + (size_t)l*65536, b2 + l*EE,
                ln2g + l*EE, ln2b + l*EE, Hb, Hbf, Wp, bp, out);
        } else {
            // last layer: even rows only; preds computed in the tail
            attn_k<1><<<256, 512, 0, stream>>>(
                Qp, Kpk, Vpk, Hb, ln1g + l*EE, ln1b + l*EE,
                W1t + (size_t)l*65536, b1 + l*EE,
                W2t + (size_t)l*65536, b2 + l*EE,
                ln2g + l*EE, ln2b + l*EE, Hb, Hbf, Wp, bp, out);
        }
    }
}